// Round 5
// baseline (256.894 us; speedup 1.0000x reference)
//
#include <hip/hip_runtime.h>
#include <math.h>

// Problem constants
#define L_SEQ   32768
#define H_DIM   256
#define P_DIM   128
#define P2      256      // 2*P interleaved (re,im)
#define T_CHUNK 32
#define NBLK    512      // GEMM blocks: 64 rows each = 2 chunks
#define ROWS    64       // rows per block

// workspace layout (float offsets)
#define WS_LB    0                      // Lambda_bar            256
#define WS_A32   256                    // Lambda_bar^32         256
#define WS_A64   512                    // Lambda_bar^64         256
#define WS_COEF  768                    // (Lb-1)/Lambda         256
#define WS_APOW  1024                   // [32][P2] Lb^{i+1}     8192
#define WS_E     9216                   // [512][P2] block summ  131072
#define WS_CB    140288                 // [512][P2] block carry 131072
#define WS_PACKS 271360                 // ushort packs (float offset)
// packs: W1h, W1l, W2h, W2l each 65536 ushorts = 131072 floats total
// grand total = 402432 floats (~1.6 MB)

typedef __attribute__((ext_vector_type(8))) short short8;
typedef __attribute__((ext_vector_type(4))) float f32x4;

// ---------------------------------------------------------------------------
__device__ __forceinline__ void split_bf16(float v, ushort& hi, ushort& lo) {
    union { float f; unsigned u; } a; a.f = v;
    unsigned r = a.u + 0x7FFFu + ((a.u >> 16) & 1u);   // RNE to bf16
    hi = (ushort)(r >> 16);
    union { unsigned u; float f; } hf; hf.u = ((unsigned)hi) << 16;
    float rem = v - hf.f;
    union { float f; unsigned u; } b; b.f = rem;
    unsigned r2 = b.u + 0x7FFFu + ((b.u >> 16) & 1u);
    lo = (ushort)(r2 >> 16);
}

// two packed complex: returns A*x + f  (layout r0,i0,r1,i1)
__device__ __forceinline__ float4 cfma2(const float4 A, const float4 x, const float4 f) {
    float4 o;
    o.x = A.x * x.x - A.y * x.y + f.x;
    o.y = A.x * x.y + A.y * x.x + f.y;
    o.z = A.z * x.z - A.w * x.w + f.z;
    o.w = A.z * x.w + A.w * x.z + f.w;
    return o;
}

// ---------------------------------------------------------------------------
// Setup 1: per-p quantities. 1 block, 128 threads.
__global__ void k_setup_p(const float* __restrict__ lre, const float* __restrict__ lim,
                          const float* __restrict__ lstep, float* __restrict__ ws) {
    int p = threadIdx.x;
    if (p >= P_DIM) return;
    float step = expf(lstep[p]);
    float lr = lre[p], li = lim[p];
    float z = lr * step, y = li * step;
    float er = expf(z);
    ws[WS_LB + 2*p]     = er * cosf(y);
    ws[WS_LB + 2*p + 1] = er * sinf(y);
    // powers in double (large angle => fp32 arg reduction bad)
    double zd = (double)z, yd = (double)y;
    {   // Lb^32 (chunk advance)
        double ed = exp(zd * 32.0);
        ws[WS_A32 + 2*p]     = (float)(ed * cos(yd * 32.0));
        ws[WS_A32 + 2*p + 1] = (float)(ed * sin(yd * 32.0));
    }
    {   // Lb^64 (block advance, 2 chunks)
        double ed = exp(zd * 64.0);
        ws[WS_A64 + 2*p]     = (float)(ed * cos(yd * 64.0));
        ws[WS_A64 + 2*p + 1] = (float)(ed * sin(yd * 64.0));
    }
    // Apow[i] = Lb^{i+1}, i = 0..31
    for (int i = 0; i < 32; i++) {
        double m = (double)(i + 1);
        double ed = exp(zd * m);
        ws[WS_APOW + i*P2 + 2*p]     = (float)(ed * cos(yd * m));
        ws[WS_APOW + i*P2 + 2*p + 1] = (float)(ed * sin(yd * m));
    }
    // coef = (Lambda_bar - 1) / Lambda
    float lbr = ws[WS_LB + 2*p], lbi = ws[WS_LB + 2*p + 1];
    float a = lbr - 1.0f, b = lbi;
    float den = lr*lr + li*li;
    ws[WS_COEF + 2*p]     = (a*lr + b*li) / den;
    ws[WS_COEF + 2*p + 1] = (b*lr - a*li) / den;
}

// ---------------------------------------------------------------------------
// Setup 2: build split-bf16 packed weights, layout [n][k] (k contiguous).
__global__ void k_setup_mats(const float* __restrict__ B, const float* __restrict__ C,
                             const float* __restrict__ coef,
                             ushort* __restrict__ w1h, ushort* __restrict__ w1l,
                             ushort* __restrict__ w2h, ushort* __restrict__ w2l) {
    int t = blockIdx.x * blockDim.x + threadIdx.x;   // 0..16383
    for (int e = t; e < P_DIM * H_DIM; e += 64 * 256) {
        int p = e >> 8;          // 0..127
        int h = e & 255;         // 0..255
        float br = B[(size_t)(p*H_DIM + h)*2 + 0];
        float bi = B[(size_t)(p*H_DIM + h)*2 + 1];
        float cr = coef[2*p], ci = coef[2*p + 1];
        float v1r = cr*br - ci*bi;
        float v1i = cr*bi + ci*br;
        ushort hi, lo;
        split_bf16(v1r, hi, lo);
        w1h[(size_t)(2*p)*256 + h] = hi;  w1l[(size_t)(2*p)*256 + h] = lo;
        split_bf16(v1i, hi, lo);
        w1h[(size_t)(2*p+1)*256 + h] = hi; w1l[(size_t)(2*p+1)*256 + h] = lo;
        float Cr = C[(size_t)(h*P_DIM + p)*2 + 0];
        float Ci = C[(size_t)(h*P_DIM + p)*2 + 1];
        split_bf16(2.0f*Cr, hi, lo);
        w2h[(size_t)h*256 + 2*p] = hi;    w2l[(size_t)h*256 + 2*p] = lo;
        split_bf16(-2.0f*Ci, hi, lo);
        w2h[(size_t)h*256 + 2*p+1] = hi;  w2l[(size_t)h*256 + 2*p+1] = lo;
    }
}

// ---------------------------------------------------------------------------
// Carry: serial scan over 512 block summaries. 1 block, 64 threads.
// cb[s] = carry at start of block s;  cb[s+1] = A64*cb[s] + E[s]
__global__ void k_carry(const float* __restrict__ E, float* __restrict__ cb,
                        const float* __restrict__ a64) {
    const int q = threadIdx.x;   // 0..63
    const float4 A = *(const float4*)(a64 + 4 * q);
    float4 c = make_float4(0.f, 0.f, 0.f, 0.f);
    #pragma unroll 8
    for (int s = 0; s < NBLK; s++) {
        *(float4*)(cb + (size_t)s * P2 + 4 * q) = c;
        const float4 e = *(const float4*)(E + (size_t)s * P2 + 4 * q);
        c = cfma2(A, c, e);
    }
}

// ---------------------------------------------------------------------------
// MFMA split-bf16 GEMM: C[l][n] = sum_k A[l][k] * W[k][n]
// M=32768 (512 blocks x 64 rows), N=256 (full N -> in-place safe), K=256.
// 256 threads = 4 waves, wave grid 2M x 2N; per wave 2x8 tiles of 16x16x32.
// A and B staged in LDS; next k-slice register-prefetched during compute.
// BSPLIT: use B lo-pack (3 MFMA) else 2 MFMA (hi*hi + lo*hi).
// APPLY : staging adds Lb^{i+1} * carry (chunk carries rebuilt in LDS).
// SCAN  : post-epilogue in-place local scan of the 2 chunks + E_b out.
#define SAK 40   // LDS k-stride (ushorts): 32 + 8 pad
#define SBK 40

template<bool EPI, bool APPLY, bool SCAN, bool BSPLIT>
__global__ __launch_bounds__(256, 2) void k_gemm_mfma(
        const float* A, const ushort* __restrict__ Wh, const ushort* __restrict__ Wl,
        float* Cmat, const float* __restrict__ Dv, const float* __restrict__ U,
        const float* __restrict__ ws, float* __restrict__ Eout,
        const float* __restrict__ cbin) {
    __shared__ ushort Ah[ROWS * SAK];
    __shared__ ushort Al[ROWS * SAK];
    __shared__ ushort Bh[256 * SBK];
    __shared__ ushort Bl[BSPLIT ? 256 * SBK : 8];
    __shared__ float  XC[2 * P2];       // chunk-end states (SCAN) / carries (APPLY)
    const int t      = threadIdx.x;
    const int lane   = t & 63;
    const int wave   = t >> 6;        // 0..3
    const int wm     = wave & 1;      // M half (32 rows)
    const int wn     = wave >> 1;     // N half (128 cols)
    const int lane16 = lane & 15;
    const int quad   = lane >> 4;
    const int blk    = blockIdx.x;
    const int l0     = blk * ROWS;

    // --- APPLY prologue: rebuild per-chunk carries into LDS ---------------
    if (APPLY) {
        if (t < 64) {
            const float4 A32 = *(const float4*)(ws + WS_A32 + 4 * t);
            float4 c = *(const float4*)(cbin + (size_t)blk * P2 + 4 * t);
            *(float4*)(XC + 4 * t) = c;
            const float4 xe = *(const float4*)(A + (size_t)(l0 + 31) * 256 + 4 * t);
            c = cfma2(A32, c, xe);
            *(float4*)(XC + P2 + 4 * t) = c;
        }
        __syncthreads();
    }

    f32x4 acc[2][8];
    #pragma unroll
    for (int i = 0; i < 2; i++)
        #pragma unroll
        for (int j = 0; j < 8; j++) acc[i][j] = (f32x4){0.f, 0.f, 0.f, 0.f};

    // A staging: 64 rows x 8 float4 = 512 -> 2/thread
    const int sm0 = t >> 3;            // 0..31
    const int sm1 = (256 + t) >> 3;    // 32..63
    const int sc4 = t & 7;
    // B staging: 256 n x 4 uint4 = 1024 -> 4/thread/pack
    const int sbn = t >> 2;            // wait recomputed in loop (j varies)

    // register prefetch buffers
    float4 fA0, fA1;
    uint4  rBh[4], rBl[4];

    // preload kt = 0
    fA0 = *(const float4*)(A + (size_t)(l0 + sm0) * 256 + sc4 * 4);
    fA1 = *(const float4*)(A + (size_t)(l0 + sm1) * 256 + sc4 * 4);
    #pragma unroll
    for (int j = 0; j < 4; j++) {
        int idx = j * 256 + t;
        int n = idx >> 2, c = idx & 3;
        rBh[j] = *(const uint4*)(Wh + (size_t)n * 256 + c * 8);
        if (BSPLIT) rBl[j] = *(const uint4*)(Wl + (size_t)n * 256 + c * 8);
    }

    for (int kt = 0; kt < 8; kt++) {
        const int k0 = kt * 32;
        if (kt) __syncthreads();         // readers of previous slice done
        // store staged A (APPLY transform + split) to LDS
        {
            float4 ff[2] = {fA0, fA1};
            int    mm[2] = {sm0, sm1};
            #pragma unroll
            for (int j = 0; j < 2; j++) {
                float4 f = ff[j];
                int m = mm[j];
                if (APPLY) {
                    int g = m >> 5, i = m & 31;
                    int jk = k0 + sc4 * 4;
                    const float4 ap = *(const float4*)(ws + WS_APOW + (size_t)i * P2 + jk);
                    const float4 cr = *(const float4*)(XC + g * P2 + jk);
                    f = cfma2(ap, cr, f);
                }
                ushort4 h4, l4;
                split_bf16(f.x, h4.x, l4.x);
                split_bf16(f.y, h4.y, l4.y);
                split_bf16(f.z, h4.z, l4.z);
                split_bf16(f.w, h4.w, l4.w);
                *(ushort4*)(&Ah[m * SAK + sc4 * 4]) = h4;
                *(ushort4*)(&Al[m * SAK + sc4 * 4]) = l4;
            }
        }
        // store staged B to LDS
        #pragma unroll
        for (int j = 0; j < 4; j++) {
            int idx = j * 256 + t;
            int n = idx >> 2, c = idx & 3;
            *(uint4*)(&Bh[n * SBK + c * 8]) = rBh[j];
            if (BSPLIT) *(uint4*)(&Bl[n * SBK + c * 8]) = rBl[j];
        }
        __syncthreads();                 // staging visible
        // prefetch next k-slice (latency overlaps the MFMA phase below)
        if (kt < 7) {
            const int kn = k0 + 32;
            fA0 = *(const float4*)(A + (size_t)(l0 + sm0) * 256 + kn + sc4 * 4);
            fA1 = *(const float4*)(A + (size_t)(l0 + sm1) * 256 + kn + sc4 * 4);
            #pragma unroll
            for (int j = 0; j < 4; j++) {
                int idx = j * 256 + t;
                int n = idx >> 2, c = idx & 3;
                rBh[j] = *(const uint4*)(Wh + (size_t)n * 256 + kn + c * 8);
                if (BSPLIT) rBl[j] = *(const uint4*)(Wl + (size_t)n * 256 + kn + c * 8);
            }
        }
        // fragments + MFMA
        short8 ah[2], alo[2], bh[8], blo[8];
        #pragma unroll
        for (int mf = 0; mf < 2; mf++) {
            int m = wm * 32 + mf * 16 + lane16;
            ah[mf]  = *(const short8*)(&Ah[m * SAK + quad * 8]);
            alo[mf] = *(const short8*)(&Al[m * SAK + quad * 8]);
        }
        #pragma unroll
        for (int nf = 0; nf < 8; nf++) {
            int n = wn * 128 + nf * 16 + lane16;
            bh[nf] = *(const short8*)(&Bh[n * SBK + quad * 8]);
            if (BSPLIT) blo[nf] = *(const short8*)(&Bl[n * SBK + quad * 8]);
        }
        #pragma unroll
        for (int mf = 0; mf < 2; mf++)
            #pragma unroll
            for (int nf = 0; nf < 8; nf++) {
                acc[mf][nf] = __builtin_amdgcn_mfma_f32_16x16x32_bf16(ah[mf],  bh[nf],  acc[mf][nf], 0, 0, 0);
                if (BSPLIT)
                    acc[mf][nf] = __builtin_amdgcn_mfma_f32_16x16x32_bf16(ah[mf], blo[nf], acc[mf][nf], 0, 0, 0);
                acc[mf][nf] = __builtin_amdgcn_mfma_f32_16x16x32_bf16(alo[mf], bh[nf],  acc[mf][nf], 0, 0, 0);
            }
    }

    // epilogue: C/D layout col=lane&15, row=quad*4+reg
    #pragma unroll
    for (int mf = 0; mf < 2; mf++) {
        #pragma unroll
        for (int nf = 0; nf < 8; nf++) {
            int row0 = l0 + wm * 32 + mf * 16 + quad * 4;
            int col  = wn * 128 + nf * 16 + lane16;
            #pragma unroll
            for (int r = 0; r < 4; r++) {
                float v = acc[mf][nf][r];
                if (EPI) {
                    v += Dv[col] * U[(size_t)(row0 + r) * 256 + col];
                }
                Cmat[(size_t)(row0 + r) * 256 + col] = v;
            }
        }
    }

    // --- SCAN epilogue: in-place local scan of the 2 chunks + E_b ---------
    if (SCAN) {
        __syncthreads();   // full tile written (vmcnt drained at barrier)
        if (wave < 2) {
            const float4 Alb = *(const float4*)(ws + WS_LB + 4 * lane);
            float* base = Cmat + (size_t)(l0 + wave * 32) * 256 + 4 * lane;
            float4 x = make_float4(0.f, 0.f, 0.f, 0.f);
            #pragma unroll 8
            for (int i = 0; i < T_CHUNK; i++) {
                const float4 f = *(const float4*)(base + (size_t)i * 256);
                x = cfma2(Alb, x, f);
                *(float4*)(base + (size_t)i * 256) = x;
            }
            *(float4*)(XC + wave * P2 + 4 * lane) = x;
        }
        __syncthreads();
        if (wave == 0) {
            const float4 A32 = *(const float4*)(ws + WS_A32 + 4 * lane);
            const float4 x0  = *(const float4*)(XC + 4 * lane);
            const float4 x1  = *(const float4*)(XC + P2 + 4 * lane);
            const float4 e   = cfma2(A32, x0, x1);
            *(float4*)(Eout + (size_t)blk * P2 + 4 * lane) = e;
        }
    }
}

// ---------------------------------------------------------------------------
extern "C" void kernel_launch(void* const* d_in, const int* in_sizes, int n_in,
                              void* d_out, int out_size, void* d_ws, size_t ws_size,
                              hipStream_t stream) {
    const float* lre   = (const float*)d_in[0];  // Lambda_re (P)
    const float* lim   = (const float*)d_in[1];  // Lambda_im (P)
    const float* B     = (const float*)d_in[2];  // (P,H,2)
    const float* C     = (const float*)d_in[3];  // (H,P,2)
    const float* D     = (const float*)d_in[4];  // (H)
    const float* lstep = (const float*)d_in[5];  // (P)
    const float* u     = (const float*)d_in[6];  // (L,H)
    float* out = (float*)d_out;                  // (L,H) -- also Bu/xs scratch
    float* ws  = (float*)d_ws;
    ushort* wpk = (ushort*)(ws + WS_PACKS);
    ushort* w1h = wpk;
    ushort* w1l = wpk + 65536;
    ushort* w2h = wpk + 131072;
    ushort* w2l = wpk + 196608;

    k_setup_p<<<1, 128, 0, stream>>>(lre, lim, lstep, ws);
    k_setup_mats<<<64, 256, 0, stream>>>(B, C, ws + WS_COEF, w1h, w1l, w2h, w2l);
    // GEMM1: Bu = u @ W1 -> d_out, fused local scan + block summaries E
    k_gemm_mfma<false, false, true, true><<<NBLK, 256, 0, stream>>>(
        u, w1h, w1l, out, nullptr, nullptr, ws, ws + WS_E, nullptr);
    // carry across 512 blocks
    k_carry<<<1, 64, 0, stream>>>(ws + WS_E, ws + WS_CB, ws + WS_A64);
    // GEMM2: out = (xs_local + Lb^{i+1} carry) @ W2 + D*u  (in place, B hi-only)
    k_gemm_mfma<true, true, false, false><<<NBLK, 256, 0, stream>>>(
        out, w2h, w2l, out, D, u, ws, nullptr, ws + WS_CB);
}

// Round 6
// 221.103 us; speedup vs baseline: 1.1619x; 1.1619x over previous
//
#include <hip/hip_runtime.h>
#include <math.h>

// Problem constants
#define L_SEQ   32768
#define H_DIM   256
#define P_DIM   128
#define P2      256      // 2*P interleaved (re,im)
#define T_CHUNK 32
#define NBLK    512      // GEMM blocks: 64 rows each = 2 chunks
#define ROWS    64       // rows per block

// workspace layout (float offsets)
#define WS_LB    0                      // Lambda_bar            256
#define WS_A32   256                    // Lambda_bar^32         256
#define WS_A64   512                    // Lambda_bar^64         256
#define WS_COEF  768                    // (Lb-1)/Lambda         256
#define WS_APOW  1024                   // [32][P2] Lb^{i+1}     8192
#define WS_E     9216                   // [512][P2] block summ  131072
#define WS_CB    140288                 // [512][P2] block carry 131072
#define WS_PACKS 271360                 // ushort packs (float offset)
// packs: W1h, W1l, W2h, W2l each 65536 ushorts = 131072 floats total

typedef __attribute__((ext_vector_type(8))) short short8;
typedef __attribute__((ext_vector_type(4))) float f32x4;

#define SAK 264   // LDS k-stride (ushorts) for full A tile: 256 + 8 pad
#define STL 260   // LDS float stride for scan tile

// ---------------------------------------------------------------------------
__device__ __forceinline__ void split_bf16(float v, ushort& hi, ushort& lo) {
    union { float f; unsigned u; } a; a.f = v;
    unsigned r = a.u + 0x7FFFu + ((a.u >> 16) & 1u);   // RNE to bf16
    hi = (ushort)(r >> 16);
    union { unsigned u; float f; } hf; hf.u = ((unsigned)hi) << 16;
    float rem = v - hf.f;
    union { float f; unsigned u; } b; b.f = rem;
    unsigned r2 = b.u + 0x7FFFu + ((b.u >> 16) & 1u);
    lo = (ushort)(r2 >> 16);
}

// two packed complex: returns A*x + f  (layout r0,i0,r1,i1)
__device__ __forceinline__ float4 cfma2(const float4 A, const float4 x, const float4 f) {
    float4 o;
    o.x = A.x * x.x - A.y * x.y + f.x;
    o.y = A.x * x.y + A.y * x.x + f.y;
    o.z = A.z * x.z - A.w * x.w + f.z;
    o.w = A.z * x.w + A.w * x.z + f.w;
    return o;
}

// ---------------------------------------------------------------------------
// Setup 1: per-p quantities. 1 block, 128 threads.
__global__ void k_setup_p(const float* __restrict__ lre, const float* __restrict__ lim,
                          const float* __restrict__ lstep, float* __restrict__ ws) {
    int p = threadIdx.x;
    if (p >= P_DIM) return;
    float step = expf(lstep[p]);
    float lr = lre[p], li = lim[p];
    float z = lr * step, y = li * step;
    float er = expf(z);
    ws[WS_LB + 2*p]     = er * cosf(y);
    ws[WS_LB + 2*p + 1] = er * sinf(y);
    double zd = (double)z, yd = (double)y;
    {   // Lb^32 (chunk advance)
        double ed = exp(zd * 32.0);
        ws[WS_A32 + 2*p]     = (float)(ed * cos(yd * 32.0));
        ws[WS_A32 + 2*p + 1] = (float)(ed * sin(yd * 32.0));
    }
    {   // Lb^64 (block advance, 2 chunks)
        double ed = exp(zd * 64.0);
        ws[WS_A64 + 2*p]     = (float)(ed * cos(yd * 64.0));
        ws[WS_A64 + 2*p + 1] = (float)(ed * sin(yd * 64.0));
    }
    for (int i = 0; i < 32; i++) {   // Apow[i] = Lb^{i+1}
        double m = (double)(i + 1);
        double ed = exp(zd * m);
        ws[WS_APOW + i*P2 + 2*p]     = (float)(ed * cos(yd * m));
        ws[WS_APOW + i*P2 + 2*p + 1] = (float)(ed * sin(yd * m));
    }
    float lbr = ws[WS_LB + 2*p], lbi = ws[WS_LB + 2*p + 1];
    float a = lbr - 1.0f, b = lbi;
    float den = lr*lr + li*li;
    ws[WS_COEF + 2*p]     = (a*lr + b*li) / den;
    ws[WS_COEF + 2*p + 1] = (b*lr - a*li) / den;
}

// ---------------------------------------------------------------------------
// Setup 2: build split-bf16 packed weights, layout [n][k] (k contiguous).
__global__ void k_setup_mats(const float* __restrict__ B, const float* __restrict__ C,
                             const float* __restrict__ coef,
                             ushort* __restrict__ w1h, ushort* __restrict__ w1l,
                             ushort* __restrict__ w2h, ushort* __restrict__ w2l) {
    int t = blockIdx.x * blockDim.x + threadIdx.x;   // 0..16383
    for (int e = t; e < P_DIM * H_DIM; e += 64 * 256) {
        int p = e >> 8;          // 0..127
        int h = e & 255;         // 0..255
        float br = B[(size_t)(p*H_DIM + h)*2 + 0];
        float bi = B[(size_t)(p*H_DIM + h)*2 + 1];
        float cr = coef[2*p], ci = coef[2*p + 1];
        float v1r = cr*br - ci*bi;
        float v1i = cr*bi + ci*br;
        ushort hi, lo;
        split_bf16(v1r, hi, lo);
        w1h[(size_t)(2*p)*256 + h] = hi;  w1l[(size_t)(2*p)*256 + h] = lo;
        split_bf16(v1i, hi, lo);
        w1h[(size_t)(2*p+1)*256 + h] = hi; w1l[(size_t)(2*p+1)*256 + h] = lo;
        float Cr = C[(size_t)(h*P_DIM + p)*2 + 0];
        float Ci = C[(size_t)(h*P_DIM + p)*2 + 1];
        split_bf16(2.0f*Cr, hi, lo);
        w2h[(size_t)h*256 + 2*p] = hi;    w2l[(size_t)h*256 + 2*p] = lo;
        split_bf16(-2.0f*Ci, hi, lo);
        w2h[(size_t)h*256 + 2*p+1] = hi;  w2l[(size_t)h*256 + 2*p+1] = lo;
    }
}

// ---------------------------------------------------------------------------
// Carry: serial scan over 512 block summaries. 1 block, 64 threads.
__global__ void k_carry(const float* __restrict__ E, float* __restrict__ cb,
                        const float* __restrict__ a64) {
    const int q = threadIdx.x;   // 0..63
    const float4 A = *(const float4*)(a64 + 4 * q);
    float4 c = make_float4(0.f, 0.f, 0.f, 0.f);
    #pragma unroll 8
    for (int s = 0; s < NBLK; s++) {
        *(float4*)(cb + (size_t)s * P2 + 4 * q) = c;
        const float4 e = *(const float4*)(E + (size_t)s * P2 + 4 * q);
        c = cfma2(A, c, e);
    }
}

// ---------------------------------------------------------------------------
// MFMA split-bf16 GEMM: C[l][n] = sum_k A[l][k] * W[k][n]
// M=32768 (512 blocks x 64 rows), N=256 (full N -> in-place safe), K=256.
// 256 threads = 4 waves, wave grid 2M x 2N; per wave 2x8 tiles of 16x16x32.
// A tile staged ONCE in LDS (split bf16); K-loop has no barriers; B frags
// read per-kt from global (L2-resident weights). No register prefetch.
// BSPLIT: B lo-pack used (3 MFMA) else 2 MFMA.
// APPLY : staging adds Lb^{i+1} * carry (chunk carries rebuilt in LDS).
// SCAN  : acc dumped to LDS (aliases dead A-staging), scanned there, xs
//         written once to global + block summary E. No in-place re-read.
template<bool EPI, bool APPLY, bool SCAN, bool BSPLIT>
__global__ __launch_bounds__(256, 2) void k_gemm_mfma(
        const float* A, const ushort* __restrict__ Wh, const ushort* __restrict__ Wl,
        float* Cmat, const float* __restrict__ Dv, const float* __restrict__ U,
        const float* __restrict__ ws, float* __restrict__ Eout,
        const float* __restrict__ cbin) {
    __shared__ float4 SMraw[4224];           // 67584 B: A staging / scan tile
    __shared__ float  XC[2 * P2];            // chunk carries (APPLY) / ends (SCAN)
    ushort* Ah   = (ushort*)SMraw;           // [64][SAK]
    ushort* Al   = Ah + ROWS * SAK;
    float*  Tile = (float*)SMraw;            // [64][STL]  (SCAN, aliases Ah/Al)

    const int t      = threadIdx.x;
    const int lane   = t & 63;
    const int wave   = t >> 6;        // 0..3
    const int wm     = wave & 1;      // M half (32 rows)
    const int wn     = wave >> 1;     // N half (128 cols)
    const int lane16 = lane & 15;
    const int quad   = lane >> 4;
    const int blk    = blockIdx.x;
    const int l0     = blk * ROWS;

    // --- APPLY prologue: rebuild per-chunk carries into LDS ---------------
    if (APPLY) {
        if (t < 64) {
            const float4 A32 = *(const float4*)(ws + WS_A32 + 4 * t);
            float4 c = *(const float4*)(cbin + (size_t)blk * P2 + 4 * t);
            *(float4*)(XC + 4 * t) = c;
            const float4 xe = *(const float4*)(A + (size_t)(l0 + 31) * 256 + 4 * t);
            c = cfma2(A32, c, xe);
            *(float4*)(XC + P2 + 4 * t) = c;
        }
        __syncthreads();
    }

    // --- stage full A tile (64 x 256) into LDS, split bf16 ----------------
    #pragma unroll
    for (int j = 0; j < 16; j++) {
        int idx = j * 256 + t;
        int m  = idx >> 6;           // 0..63
        int c4 = idx & 63;           // float4 col 0..63
        float4 f = *(const float4*)(A + (size_t)(l0 + m) * 256 + c4 * 4);
        if (APPLY) {
            int g = m >> 5, i = m & 31;
            const float4 ap = *(const float4*)(ws + WS_APOW + (size_t)i * P2 + c4 * 4);
            const float4 cr = *(const float4*)(XC + g * P2 + c4 * 4);
            f = cfma2(ap, cr, f);
        }
        ushort4 h4, l4;
        split_bf16(f.x, h4.x, l4.x);
        split_bf16(f.y, h4.y, l4.y);
        split_bf16(f.z, h4.z, l4.z);
        split_bf16(f.w, h4.w, l4.w);
        *(ushort4*)(&Ah[m * SAK + c4 * 4]) = h4;
        *(ushort4*)(&Al[m * SAK + c4 * 4]) = l4;
    }
    __syncthreads();

    f32x4 acc[2][8];
    #pragma unroll
    for (int i = 0; i < 2; i++)
        #pragma unroll
        for (int j = 0; j < 8; j++) acc[i][j] = (f32x4){0.f, 0.f, 0.f, 0.f};

    // b-frag base: 4 quads of one lane16 form a contiguous 64 B L2 segment
    const ushort* WhB = Wh + (size_t)(wn * 128 + lane16) * 256 + quad * 8;
    const ushort* WlB = Wl + (size_t)(wn * 128 + lane16) * 256 + quad * 8;

    // --- K-loop: no barriers, no prefetch registers -----------------------
    #pragma unroll
    for (int kt = 0; kt < 8; kt++) {
        const int k0 = kt * 32;
        short8 ah[2], alo[2];
        #pragma unroll
        for (int mf = 0; mf < 2; mf++) {
            int m = wm * 32 + mf * 16 + lane16;
            ah[mf]  = *(const short8*)(&Ah[m * SAK + k0 + quad * 8]);
            alo[mf] = *(const short8*)(&Al[m * SAK + k0 + quad * 8]);
        }
        short8 bh[8], blo[8];
        #pragma unroll
        for (int nf = 0; nf < 8; nf++) {
            bh[nf] = *(const short8*)(WhB + (size_t)nf * 16 * 256 + k0);
            if (BSPLIT) blo[nf] = *(const short8*)(WlB + (size_t)nf * 16 * 256 + k0);
        }
        #pragma unroll
        for (int mf = 0; mf < 2; mf++)
            #pragma unroll
            for (int nf = 0; nf < 8; nf++) {
                acc[mf][nf] = __builtin_amdgcn_mfma_f32_16x16x32_bf16(ah[mf],  bh[nf],  acc[mf][nf], 0, 0, 0);
                if (BSPLIT)
                    acc[mf][nf] = __builtin_amdgcn_mfma_f32_16x16x32_bf16(ah[mf], blo[nf], acc[mf][nf], 0, 0, 0);
                acc[mf][nf] = __builtin_amdgcn_mfma_f32_16x16x32_bf16(alo[mf], bh[nf],  acc[mf][nf], 0, 0, 0);
            }
    }

    if (!SCAN) {
        // direct epilogue: C/D layout col=lane&15, row=quad*4+reg
        #pragma unroll
        for (int mf = 0; mf < 2; mf++) {
            #pragma unroll
            for (int nf = 0; nf < 8; nf++) {
                int row0 = l0 + wm * 32 + mf * 16 + quad * 4;
                int col  = wn * 128 + nf * 16 + lane16;
                #pragma unroll
                for (int r = 0; r < 4; r++) {
                    float v = acc[mf][nf][r];
                    if (EPI) v += Dv[col] * U[(size_t)(row0 + r) * 256 + col];
                    Cmat[(size_t)(row0 + r) * 256 + col] = v;
                }
            }
        }
    } else {
        // dump acc into LDS tile (staging area is dead after last ds_read)
        __syncthreads();
        #pragma unroll
        for (int mf = 0; mf < 2; mf++)
            #pragma unroll
            for (int nf = 0; nf < 8; nf++) {
                int row0 = wm * 32 + mf * 16 + quad * 4;
                int col  = wn * 128 + nf * 16 + lane16;
                #pragma unroll
                for (int r = 0; r < 4; r++)
                    Tile[(row0 + r) * STL + col] = acc[mf][nf][r];
            }
        __syncthreads();
        // waves 0,1: scan chunk `wave` (32 rows) from LDS, write xs once
        if (wave < 2) {
            const float4 Alb = *(const float4*)(ws + WS_LB + 4 * lane);
            float* gbase = Cmat + (size_t)(l0 + wave * 32) * 256 + 4 * lane;
            const float* tbase = Tile + (wave * 32) * STL + 4 * lane;
            float4 x = make_float4(0.f, 0.f, 0.f, 0.f);
            #pragma unroll 8
            for (int i = 0; i < T_CHUNK; i++) {
                const float4 f = *(const float4*)(tbase + i * STL);
                x = cfma2(Alb, x, f);
                *(float4*)(gbase + (size_t)i * 256) = x;
            }
            *(float4*)(XC + wave * P2 + 4 * lane) = x;
        }
        __syncthreads();
        if (t < 64) {
            const float4 A32 = *(const float4*)(ws + WS_A32 + 4 * t);
            const float4 x0  = *(const float4*)(XC + 4 * t);
            const float4 x1  = *(const float4*)(XC + P2 + 4 * t);
            const float4 e   = cfma2(A32, x0, x1);
            *(float4*)(Eout + (size_t)blk * P2 + 4 * t) = e;
        }
    }
}

// ---------------------------------------------------------------------------
extern "C" void kernel_launch(void* const* d_in, const int* in_sizes, int n_in,
                              void* d_out, int out_size, void* d_ws, size_t ws_size,
                              hipStream_t stream) {
    const float* lre   = (const float*)d_in[0];  // Lambda_re (P)
    const float* lim   = (const float*)d_in[1];  // Lambda_im (P)
    const float* B     = (const float*)d_in[2];  // (P,H,2)
    const float* C     = (const float*)d_in[3];  // (H,P,2)
    const float* D     = (const float*)d_in[4];  // (H)
    const float* lstep = (const float*)d_in[5];  // (P)
    const float* u     = (const float*)d_in[6];  // (L,H)
    float* out = (float*)d_out;                  // (L,H) -- xs then final out
    float* ws  = (float*)d_ws;
    ushort* wpk = (ushort*)(ws + WS_PACKS);
    ushort* w1h = wpk;
    ushort* w1l = wpk + 65536;
    ushort* w2h = wpk + 131072;
    ushort* w2l = wpk + 196608;

    k_setup_p<<<1, 128, 0, stream>>>(lre, lim, lstep, ws);
    k_setup_mats<<<64, 256, 0, stream>>>(B, C, ws + WS_COEF, w1h, w1l, w2h, w2l);
    // GEMM1: xs_local = scan_local(u @ W1) -> d_out (single write), E out
    k_gemm_mfma<false, false, true, true><<<NBLK, 256, 0, stream>>>(
        u, w1h, w1l, out, nullptr, nullptr, ws, ws + WS_E, nullptr);
    // carry across 512 blocks
    k_carry<<<1, 64, 0, stream>>>(ws + WS_E, ws + WS_CB, ws + WS_A64);
    // GEMM2: out = (xs_local + Lb^{i+1} carry) @ W2 + D*u  (in place, B hi-only)
    k_gemm_mfma<true, true, false, false><<<NBLK, 256, 0, stream>>>(
        out, w2h, w2l, out, D, u, ws, nullptr, ws + WS_CB);
}